// Round 1
// baseline (202.576 us; speedup 1.0000x reference)
//
#include <hip/hip_runtime.h>
#include <hip/hip_bf16.h>

// CompanyOperationEvaluation R10: fuse K2+K3+K4 into one 512-block kernel.
//  K1 prep (unchanged): gather+cross (2048 blocks) -> high[:,128:256] +
//           weight transposes (304 blocks) + W2 (1 block).
//  K2 fused_mlp: 512 blocks x 32 rows. Per block:
//    phase 1: feat->cf0->cf1->cf2 (proven layer32), cf2 -> A_sh[:,0:128] LDS
//    phase 2: high_e gather-half loaded -> A_sh[:,128:256] (coalesced)
//    phase 3: x0 = relu(A @ W0 + b0) -> x0_sh (LDS only, never HBM)
//    phase 4: x1 = relu(x0 @ W1 + b1) -> x1_sh (aliased into b_sh)
//    phase 5: W2 GEMV + softmax + target epilogue (verbatim K4)
//  LDS: regionA 34.3KB (feat/A_sh 32x264 | buf0 | buf1; x0_sh 32x520 aliases
//  whole region after cf phase) + b_sh 36.9KB + w2_sh 4KB = 73.5KB
//  -> 2 blocks/CU, all 512 blocks co-resident.
// Removes: x0 HBM round trip (33.6MB), high[:,0:128] write + 4x A-tile
// re-reads in old K3 (~38MB), 2 kernel launches + gaps.
// Lesson bank: (R2) never feed MFMA operands from global at low occupancy;
// (R5) don't shrink M-tile-per-barrier below ~8 MFMAs/wave/chunk;
// (R6) random-gather and MFMA phases must not share a block;
// (R8) block-range fusion inherits max LDS across branches.

typedef __bf16 bf16x8 __attribute__((ext_vector_type(8)));
typedef float floatx4 __attribute__((ext_vector_type(4)));

__device__ __forceinline__ unsigned short f2bf(float x) {
  unsigned int u = __builtin_bit_cast(unsigned int, x);
  u = (u + 0x7FFFu + ((u >> 16) & 1u)) >> 16;
  return (unsigned short)u;
}

// ---------------------------------------------------------------------------
// K1 prep: blocks [0,2048) gather+cross (8 rows/block, 32 lanes/row);
// blocks [2048,2352) 32x32 transpose tiles; block 2352 W2.
// ---------------------------------------------------------------------------
__global__ __launch_bounds__(256) void prep_kernel(
    const int* __restrict__ ent_idx, const float* __restrict__ head_tab,
    const float* __restrict__ ent_tab,
    const float* __restrict__ w_cf, const float* __restrict__ w_fc,
    const float* __restrict__ w_ef, const float* __restrict__ w_fe,
    const float* __restrict__ b_c, const float* __restrict__ b_e,
    const float* __restrict__ Wf, const float* __restrict__ Wu,
    const float* __restrict__ W0, const float* __restrict__ W1,
    const float* __restrict__ W2,
    unsigned short* __restrict__ high,
    unsigned short* __restrict__ wfT, unsigned short* __restrict__ wuT,
    unsigned short* __restrict__ w0T, unsigned short* __restrict__ w1T,
    unsigned short* __restrict__ w2T) {
  __shared__ unsigned short tile[32][34];
  const int bid = blockIdx.x, tid = threadIdx.x;
  if (bid < 2048) {
    // gather + cross_compress x2 (fp32, in-register), 8 rows/block
    const int row = bid * 8 + (tid >> 5);
    const int c = (tid & 31) * 4;
    const int idx = ent_idx[row];
    float4 hv = *(const float4*)(head_tab + (size_t)idx * 128 + c);
    float4 ev = *(const float4*)(ent_tab + (size_t)idx * 128 + c);
    float h[4] = {hv.x, hv.y, hv.z, hv.w};
    float e[4] = {ev.x, ev.y, ev.z, ev.w};
    float wcf[4], wfc[4], wef[4], wfe[4];
#pragma unroll
    for (int j = 0; j < 4; ++j) {
      wcf[j] = w_cf[c + j]; wfc[j] = w_fc[c + j];
      wef[j] = w_ef[c + j]; wfe[j] = w_fe[c + j];
    }
    const float bc = b_c[0], be = b_e[0];
#pragma unroll
    for (int it = 0; it < 2; ++it) {
      float d0 = 0, d1 = 0, d2 = 0, d3 = 0;
#pragma unroll
      for (int j = 0; j < 4; ++j) {
        d0 += e[j] * wcf[j]; d1 += h[j] * wfc[j];
        d2 += e[j] * wef[j]; d3 += h[j] * wfe[j];
      }
#pragma unroll
      for (int s = 1; s < 32; s <<= 1) {
        d0 += __shfl_xor(d0, s); d1 += __shfl_xor(d1, s);
        d2 += __shfl_xor(d2, s); d3 += __shfl_xor(d3, s);
      }
      float nh[4], ne[4];
#pragma unroll
      for (int j = 0; j < 4; ++j) {
        nh[j] = h[j] * d0 + e[j] * d1 + bc;
        ne[j] = h[j] * d2 + e[j] * d3 + be;
      }
#pragma unroll
      for (int j = 0; j < 4; ++j) { h[j] = nh[j]; e[j] = ne[j]; }
    }
    uint2 v;
    v.x = (unsigned)f2bf(e[0]) | ((unsigned)f2bf(e[1]) << 16);
    v.y = (unsigned)f2bf(e[2]) | ((unsigned)f2bf(e[3]) << 16);
    *(uint2*)(high + (size_t)row * 256 + 128 + c) = v;
  } else if (bid < 2352) {
    // 32x32 transpose tiles: src (K x N) fp32 -> dst (N x K) bf16
    int t = bid - 2048;
    const float* src; unsigned short* dst; int N, K, kt, nt;
    if (t < 32)       { src = Wf; dst = wfT; N = 128; K = 256; kt = t >> 2;       nt = t & 3; }
    else if (t < 48)  { t -= 32;  src = Wu; dst = wuT; N = 128; K = 128; kt = t >> 2; nt = t & 3; }
    else if (t < 176) { t -= 48;  src = W0; dst = w0T; N = 512; K = 256; kt = t >> 4; nt = t & 15; }
    else              { t -= 176; src = W1; dst = w1T; N = 256; K = 512; kt = t >> 3; nt = t & 7; }
    {
      int r = tid >> 3, cg = (tid & 7) * 4;
      float4 v = *(const float4*)(src + (size_t)(kt * 32 + r) * N + nt * 32 + cg);
      tile[r][cg + 0] = f2bf(v.x); tile[r][cg + 1] = f2bf(v.y);
      tile[r][cg + 2] = f2bf(v.z); tile[r][cg + 3] = f2bf(v.w);
    }
    __syncthreads();
    {
      int rp = tid >> 3, cg = (tid & 7) * 4;
      uint2 o;
      o.x = (unsigned)tile[cg + 0][rp] | ((unsigned)tile[cg + 1][rp] << 16);
      o.y = (unsigned)tile[cg + 2][rp] | ((unsigned)tile[cg + 3][rp] << 16);
      *(uint2*)(dst + (size_t)(nt * 32 + rp) * K + kt * 32 + cg) = o;
    }
  } else {
    // W2 256x8 -> 8x256
#pragma unroll
    for (int i = 0; i < 8; ++i) {
      int g = tid * 8 + i, k = g >> 3, n = g & 7;
      w2T[n * 256 + k] = f2bf(W2[g]);
    }
  }
}

// ---------------------------------------------------------------------------
// layer32: proven K2 inner layer. B (128 n-rows x BK=64) staged into pad-72
// LDS; wave covers 32 rows x 32-col strip (acc[2][2]). Ends with barrier.
// ---------------------------------------------------------------------------
template <int LDA>
__device__ __forceinline__ void layer32(const unsigned short* A_sh,
                                        const unsigned short* __restrict__ BT,
                                        int K, unsigned short* b_sh,
                                        floatx4 acc[2][2]) {
  const int tid = threadIdx.x, lane = tid & 63, wave = tid >> 6;
  const int m16 = lane & 15, quad = lane >> 4;
#pragma unroll
  for (int mi = 0; mi < 2; ++mi)
#pragma unroll
    for (int ni = 0; ni < 2; ++ni) acc[mi][ni] = (floatx4){0.f, 0.f, 0.f, 0.f};
  for (int k0 = 0; k0 < K; k0 += 64) {
    __syncthreads();  // prev b_sh reads done; producer LDS writes visible
#pragma unroll
    for (int i = 0; i < 4; ++i) {
      int chunk = i * 256 + tid;
      int row = chunk >> 3, seg = chunk & 7;
      *(uint4*)&b_sh[row * 72 + seg * 8] =
          *(const uint4*)(BT + (size_t)row * K + k0 + seg * 8);
    }
    __syncthreads();
#pragma unroll
    for (int kk = 0; kk < 64; kk += 32) {
      bf16x8 a[2], b[2];
#pragma unroll
      for (int mi = 0; mi < 2; ++mi)
        a[mi] = *(const bf16x8*)&A_sh[(mi * 16 + m16) * LDA + k0 + kk + quad * 8];
#pragma unroll
      for (int ni = 0; ni < 2; ++ni)
        b[ni] = *(const bf16x8*)&b_sh[(wave * 32 + ni * 16 + m16) * 72 + kk + quad * 8];
#pragma unroll
      for (int mi = 0; mi < 2; ++mi)
#pragma unroll
        for (int ni = 0; ni < 2; ++ni)
          acc[mi][ni] = __builtin_amdgcn_mfma_f32_16x16x32_bf16(a[mi], b[ni], acc[mi][ni], 0, 0, 0);
    }
  }
  __syncthreads();
}

// ---------------------------------------------------------------------------
// K2 fused_mlp: 512 blocks x 32 rows, full per-row pipeline in one block.
// ---------------------------------------------------------------------------
__global__ __launch_bounds__(256) void fused_mlp_kernel(
    const float* __restrict__ features, const unsigned short* __restrict__ wfT,
    const unsigned short* __restrict__ wuT, const float* __restrict__ bf_,
    const float* __restrict__ bu, const unsigned short* __restrict__ high,
    const unsigned short* __restrict__ w0T, const float* __restrict__ b0,
    const unsigned short* __restrict__ w1T, const float* __restrict__ b1,
    const unsigned short* __restrict__ w2T, const float* __restrict__ b2,
    const int* __restrict__ target, float* __restrict__ out) {
  // regionA layout (shorts): [0,8448) feat_sh/A_sh 32x264;
  // [8448,12800) buf0 32x136; [12800,17152) buf1 32x136.
  // x0_sh (32x520 = 16640) aliases [0,16640) after cf phase.
  __shared__ __align__(16) unsigned short regionA[17152];   // 34.3 KB
  __shared__ __align__(16) unsigned short b_sh[256 * 72];   // 36.9 KB
  __shared__ __align__(16) unsigned short w2_sh[2048];      //  4.0 KB
  unsigned short* feat_sh = regionA;
  unsigned short* buf0 = regionA + 8448;
  unsigned short* buf1 = regionA + 12800;
  unsigned short* A_sh = regionA;   // 32x264: [cf2 | high_e] concat
  unsigned short* x0_sh = regionA;  // 32x520 (row stride 1040B = 65*16 ok)
  unsigned short* x1_sh = b_sh;     // 32x264 = 16.5 KB <= b_sh

  const int tid = threadIdx.x;
  const int r0 = blockIdx.x * 32;
  *(uint4*)&w2_sh[tid * 8] = *(const uint4*)(w2T + tid * 8);

  // stage features fp32->bf16: 2048 float4, 8/thread, coalesced
#pragma unroll
  for (int i = 0; i < 8; ++i) {
    int idx4 = i * 256 + tid;
    int row = idx4 >> 6, c = (idx4 & 63) * 4;
    float4 v = *(const float4*)(features + (size_t)(r0 + row) * 256 + c);
    uint2 o;
    o.x = (unsigned)f2bf(v.x) | ((unsigned)f2bf(v.y) << 16);
    o.y = (unsigned)f2bf(v.z) | ((unsigned)f2bf(v.w) << 16);
    *(uint2*)&feat_sh[row * 264 + c] = o;
  }
  const int lane = tid & 63, wave = tid >> 6;
  const int m16 = lane & 15, quad = lane >> 4;
  floatx4 acc[2][2];

  // ---- cf chain ----
  // L1: cf0 = relu(feat @ Wf + bf)
  layer32<264>(feat_sh, wfT, 256, b_sh, acc);
#pragma unroll
  for (int mi = 0; mi < 2; ++mi)
#pragma unroll
    for (int ni = 0; ni < 2; ++ni) {
      int col = wave * 32 + ni * 16 + m16;
      float bv = bf_[col];
#pragma unroll
      for (int r = 0; r < 4; ++r)
        buf0[(mi * 16 + quad * 4 + r) * 136 + col] =
            f2bf(fmaxf(acc[mi][ni][r] + bv, 0.f));
    }
  // high_e (gather half, from K1) -> A_sh[:,128:256]. feat_sh is dead here
  // (layer32's trailing barrier ordered all L1 A-reads before this write);
  // next reader of A_sh is behind two more barriers inside L2's layer32.
#pragma unroll
  for (int i = 0; i < 2; ++i) {
    int idx = i * 256 + tid;
    int row = idx >> 4, seg = idx & 15;
    *(uint4*)&A_sh[row * 264 + 128 + seg * 8] =
        *(const uint4*)(high + (size_t)(r0 + row) * 256 + 128 + seg * 8);
  }
  // L2: cf1 = relu(cf0 @ Wu + bu)
  layer32<136>(buf0, wuT, 128, b_sh, acc);
#pragma unroll
  for (int mi = 0; mi < 2; ++mi)
#pragma unroll
    for (int ni = 0; ni < 2; ++ni) {
      int col = wave * 32 + ni * 16 + m16;
      float bv = bu[col];
#pragma unroll
      for (int r = 0; r < 4; ++r)
        buf1[(mi * 16 + quad * 4 + r) * 136 + col] =
            f2bf(fmaxf(acc[mi][ni][r] + bv, 0.f));
    }
  // L3: cf2 = relu(cf1 @ Wu + bu) -> A_sh[:,0:128]
  layer32<136>(buf1, wuT, 128, b_sh, acc);
#pragma unroll
  for (int mi = 0; mi < 2; ++mi)
#pragma unroll
    for (int ni = 0; ni < 2; ++ni) {
      int col = wave * 32 + ni * 16 + m16;
      float bv = bu[col];
#pragma unroll
      for (int r = 0; r < 4; ++r)
        A_sh[(mi * 16 + quad * 4 + r) * 264 + col] =
            f2bf(fmaxf(acc[mi][ni][r] + bv, 0.f));
    }

  // ---- x0 = relu(A @ W0 + b0), N=512 in two halves, acc[2][8] ----
  floatx4 acc8[2][8];
#pragma unroll
  for (int mi = 0; mi < 2; ++mi)
#pragma unroll
    for (int ni = 0; ni < 8; ++ni) acc8[mi][ni] = (floatx4){0.f, 0.f, 0.f, 0.f};
  for (int k0 = 0; k0 < 256; k0 += 64) {
#pragma unroll
    for (int nh = 0; nh < 2; ++nh) {
      __syncthreads();  // covers A_sh epilogue writes + prev b_sh reads
#pragma unroll
      for (int i = 0; i < 8; ++i) {
        int chunk = i * 256 + tid;
        int row = chunk >> 3, seg = chunk & 7;
        *(uint4*)&b_sh[row * 72 + seg * 8] =
            *(const uint4*)(w0T + (size_t)(nh * 256 + row) * 256 + k0 + seg * 8);
      }
      __syncthreads();
#pragma unroll
      for (int kk = 0; kk < 64; kk += 32) {
        bf16x8 a[2], b[4];
#pragma unroll
        for (int mi = 0; mi < 2; ++mi)
          a[mi] = *(const bf16x8*)&A_sh[(mi * 16 + m16) * 264 + k0 + kk + quad * 8];
#pragma unroll
        for (int ni = 0; ni < 4; ++ni)
          b[ni] = *(const bf16x8*)&b_sh[(wave * 64 + ni * 16 + m16) * 72 + kk + quad * 8];
#pragma unroll
        for (int mi = 0; mi < 2; ++mi)
#pragma unroll
          for (int ni = 0; ni < 4; ++ni)
            acc8[mi][nh * 4 + ni] = __builtin_amdgcn_mfma_f32_16x16x32_bf16(
                a[mi], b[ni], acc8[mi][nh * 4 + ni], 0, 0, 0);
      }
    }
  }
  __syncthreads();  // all A_sh reads done before aliased x0_sh writes
#pragma unroll
  for (int mi = 0; mi < 2; ++mi)
#pragma unroll
    for (int nh = 0; nh < 2; ++nh)
#pragma unroll
      for (int ni = 0; ni < 4; ++ni) {
        int col = nh * 256 + wave * 64 + ni * 16 + m16;
        float bv = b0[col];
#pragma unroll
        for (int r = 0; r < 4; ++r)
          x0_sh[(mi * 16 + quad * 4 + r) * 520 + col] =
              f2bf(fmaxf(acc8[mi][nh * 4 + ni][r] + bv, 0.f));
      }

  // ---- x1 = relu(x0 @ W1 + b1), K=512, N=256, acc[2][4] (K4 structure) ----
  floatx4 acc4[2][4];
#pragma unroll
  for (int mi = 0; mi < 2; ++mi)
#pragma unroll
    for (int ni = 0; ni < 4; ++ni) acc4[mi][ni] = (floatx4){0.f, 0.f, 0.f, 0.f};
  for (int k0 = 0; k0 < 512; k0 += 64) {
    __syncthreads();  // orders x0_sh writes before A reads; prev b_sh reads
#pragma unroll
    for (int i = 0; i < 8; ++i) {
      int chunk = i * 256 + tid;
      int row = chunk >> 3, seg = chunk & 7;
      *(uint4*)&b_sh[row * 72 + seg * 8] =
          *(const uint4*)(w1T + (size_t)row * 512 + k0 + seg * 8);
    }
    __syncthreads();
#pragma unroll
    for (int kk = 0; kk < 64; kk += 32) {
      bf16x8 a[2], b[4];
#pragma unroll
      for (int mi = 0; mi < 2; ++mi)
        a[mi] = *(const bf16x8*)&x0_sh[(mi * 16 + m16) * 520 + k0 + kk + quad * 8];
#pragma unroll
      for (int ni = 0; ni < 4; ++ni)
        b[ni] = *(const bf16x8*)&b_sh[(wave * 64 + ni * 16 + m16) * 72 + kk + quad * 8];
#pragma unroll
      for (int mi = 0; mi < 2; ++mi)
#pragma unroll
        for (int ni = 0; ni < 4; ++ni)
          acc4[mi][ni] = __builtin_amdgcn_mfma_f32_16x16x32_bf16(a[mi], b[ni], acc4[mi][ni], 0, 0, 0);
    }
  }
  __syncthreads();  // all b_sh MFMA reads done before aliased x1 writes
#pragma unroll
  for (int mi = 0; mi < 2; ++mi)
#pragma unroll
    for (int ni = 0; ni < 4; ++ni) {
      int col = wave * 64 + ni * 16 + m16;
      float bv = b1[col];
#pragma unroll
      for (int r = 0; r < 4; ++r)
        x1_sh[(mi * 16 + quad * 4 + r) * 264 + col] = f2bf(fmaxf(acc4[mi][ni][r] + bv, 0.f));
    }
  __syncthreads();
  // W2 GEMV + softmax: 8 lanes/row, 32 elems/lane (verbatim K4)
  {
    int row = tid >> 3, q = tid & 7;
    float p[8];
#pragma unroll
    for (int n = 0; n < 8; ++n) p[n] = 0.f;
#pragma unroll
    for (int jb = 0; jb < 4; ++jb) {
      bf16x8 xv = *(const bf16x8*)&x1_sh[row * 264 + q * 32 + jb * 8];
#pragma unroll
      for (int n = 0; n < 8; ++n) {
        bf16x8 wv = *(const bf16x8*)&w2_sh[n * 256 + q * 32 + jb * 8];
#pragma unroll
        for (int j = 0; j < 8; ++j) p[n] += (float)xv[j] * (float)wv[j];
      }
    }
#pragma unroll
    for (int s = 1; s < 8; s <<= 1)
#pragma unroll
      for (int n = 0; n < 8; ++n) p[n] += __shfl_xor(p[n], s);
    if (q == 0) {
      float mx = -1e30f;
#pragma unroll
      for (int n = 0; n < 8; ++n) {
        p[n] = fmaxf(p[n] + b2[n], 0.f);
        mx = fmaxf(mx, p[n]);
      }
      float sum = 0.f;
#pragma unroll
      for (int n = 0; n < 8; ++n) { p[n] = __expf(p[n] - mx); sum += p[n]; }
      const float inv = 1.f / sum;
      const int gr = r0 + row;
      float4 o0 = {p[0] * inv, p[1] * inv, p[2] * inv, p[3] * inv};
      float4 o1 = {p[4] * inv, p[5] * inv, p[6] * inv, p[7] * inv};
      *(float4*)(out + (size_t)gr * 8) = o0;
      *(float4*)(out + (size_t)gr * 8 + 4) = o1;
      out[16384 * 8 + gr] = (float)target[gr];
    }
  }
}

extern "C" void kernel_launch(void* const* d_in, const int* in_sizes, int n_in,
                              void* d_out, int out_size, void* d_ws, size_t ws_size,
                              hipStream_t stream) {
  const float* features = (const float*)d_in[0];
  const int* ent_idx    = (const int*)d_in[1];
  const int* target     = (const int*)d_in[2];
  const float* Wf  = (const float*)d_in[3];
  const float* bf_ = (const float*)d_in[4];
  const float* Wu  = (const float*)d_in[5];
  const float* bu  = (const float*)d_in[6];
  const float* w_cf = (const float*)d_in[7];
  const float* w_fc = (const float*)d_in[8];
  const float* w_ef = (const float*)d_in[9];
  const float* w_fe = (const float*)d_in[10];
  const float* b_c  = (const float*)d_in[11];
  const float* b_e  = (const float*)d_in[12];
  const float* head_tab = (const float*)d_in[13];
  const float* ent_tab  = (const float*)d_in[14];
  const float* W0 = (const float*)d_in[15];
  const float* b0 = (const float*)d_in[16];
  const float* W1 = (const float*)d_in[17];
  const float* b1 = (const float*)d_in[18];
  const float* W2 = (const float*)d_in[19];
  const float* b2 = (const float*)d_in[20];
  float* out = (float*)d_out;

  unsigned short* ws = (unsigned short*)d_ws;
  size_t off = 0;
  auto alloc = [&](size_t n) { unsigned short* p = ws + off; off += n; return p; };
  unsigned short* high = alloc(16384ull * 256);
  unsigned short* wfT  = alloc(32768);
  unsigned short* wuT  = alloc(16384);
  unsigned short* w0T  = alloc(131072);
  unsigned short* w1T  = alloc(131072);
  unsigned short* w2T  = alloc(2048);
  (void)ws_size; (void)in_sizes; (void)n_in; (void)out_size;

  // K1: gather+cross -> high[:,128:256] + weight transposes
  prep_kernel<<<2353, 256, 0, stream>>>(ent_idx, head_tab, ent_tab,
      w_cf, w_fc, w_ef, w_fe, b_c, b_e, Wf, Wu, W0, W1, W2,
      high, wfT, wuT, w0T, w1T, w2T);
  // K2: full fused per-row pipeline (cf chain + x0 + x1 + W2/softmax)
  fused_mlp_kernel<<<512, 256, 0, stream>>>(features, wfT, wuT, bf_, bu,
      high, w0T, b0, w1T, b1, w2T, b2, target, out);
}

// Round 2
// 188.170 us; speedup vs baseline: 1.0766x; 1.0766x over previous
//
#include <hip/hip_runtime.h>
#include <hip/hip_bf16.h>

// CompanyOperationEvaluation R11: fused K2+K3+K4 with 2-phase pipelined
// staging (T3-minimum template).
//  K1 prep (unchanged): gather+cross (2048 blocks) -> high[:,128:256] +
//           weight transposes (304 blocks) + W2 (1 block).
//  K2 fused_mlp: 512 blocks x 32 rows. Every GEMM phase is a double-buffered
//  B-staging loop with ONE raw barrier per K-step:
//    iter t: [issue loads t+2 -> regs] [MFMA buf(t&1)] [ds_write buf((t+1)&1)]
//            [s_waitcnt lgkmcnt(0); s_barrier; sched_barrier(0)]
//  Prefetch global loads stay in flight across the raw barrier (no vmcnt(0)
//  drain, unlike __syncthreads) -> L2 weight-load latency hidden under MFMA.
//  b_sh = 2 x (128 rows x 72) halves; N>128 phases run as N-passes of 128
//  (8 MFMAs/wave/step, lesson R5). LDS total 75264 B -> 2 blocks/CU.
//  high_e prefetched into regs at kernel start, written to A_sh post-L1.
// Lesson bank: (R2) never feed MFMA operands from global at low occupancy;
// (R5) don't shrink below ~8 MFMAs/wave/chunk; (R6) random-gather and MFMA
// phases must not share a block; (R8) fusion inherits max LDS across
// branches; (R10) fusion without load-pipelining is latency-bound — every
// __syncthreads K-step exposes full L2 latency via the vmcnt(0) drain.

typedef __bf16 bf16x8 __attribute__((ext_vector_type(8)));
typedef float floatx4 __attribute__((ext_vector_type(4)));

__device__ __forceinline__ unsigned short f2bf(float x) {
  unsigned int u = __builtin_bit_cast(unsigned int, x);
  u = (u + 0x7FFFu + ((u >> 16) & 1u)) >> 16;
  return (unsigned short)u;
}

#define PHASE_BAR()                                      \
  do {                                                   \
    asm volatile("s_waitcnt lgkmcnt(0)" ::: "memory");   \
    __builtin_amdgcn_s_barrier();                        \
    __builtin_amdgcn_sched_barrier(0);                   \
  } while (0)

// ---------------------------------------------------------------------------
// K1 prep: blocks [0,2048) gather+cross (8 rows/block, 32 lanes/row);
// blocks [2048,2352) 32x32 transpose tiles; block 2352 W2.
// ---------------------------------------------------------------------------
__global__ __launch_bounds__(256) void prep_kernel(
    const int* __restrict__ ent_idx, const float* __restrict__ head_tab,
    const float* __restrict__ ent_tab,
    const float* __restrict__ w_cf, const float* __restrict__ w_fc,
    const float* __restrict__ w_ef, const float* __restrict__ w_fe,
    const float* __restrict__ b_c, const float* __restrict__ b_e,
    const float* __restrict__ Wf, const float* __restrict__ Wu,
    const float* __restrict__ W0, const float* __restrict__ W1,
    const float* __restrict__ W2,
    unsigned short* __restrict__ high,
    unsigned short* __restrict__ wfT, unsigned short* __restrict__ wuT,
    unsigned short* __restrict__ w0T, unsigned short* __restrict__ w1T,
    unsigned short* __restrict__ w2T) {
  __shared__ unsigned short tile[32][34];
  const int bid = blockIdx.x, tid = threadIdx.x;
  if (bid < 2048) {
    // gather + cross_compress x2 (fp32, in-register), 8 rows/block
    const int row = bid * 8 + (tid >> 5);
    const int c = (tid & 31) * 4;
    const int idx = ent_idx[row];
    float4 hv = *(const float4*)(head_tab + (size_t)idx * 128 + c);
    float4 ev = *(const float4*)(ent_tab + (size_t)idx * 128 + c);
    float h[4] = {hv.x, hv.y, hv.z, hv.w};
    float e[4] = {ev.x, ev.y, ev.z, ev.w};
    float wcf[4], wfc[4], wef[4], wfe[4];
#pragma unroll
    for (int j = 0; j < 4; ++j) {
      wcf[j] = w_cf[c + j]; wfc[j] = w_fc[c + j];
      wef[j] = w_ef[c + j]; wfe[j] = w_fe[c + j];
    }
    const float bc = b_c[0], be = b_e[0];
#pragma unroll
    for (int it = 0; it < 2; ++it) {
      float d0 = 0, d1 = 0, d2 = 0, d3 = 0;
#pragma unroll
      for (int j = 0; j < 4; ++j) {
        d0 += e[j] * wcf[j]; d1 += h[j] * wfc[j];
        d2 += e[j] * wef[j]; d3 += h[j] * wfe[j];
      }
#pragma unroll
      for (int s = 1; s < 32; s <<= 1) {
        d0 += __shfl_xor(d0, s); d1 += __shfl_xor(d1, s);
        d2 += __shfl_xor(d2, s); d3 += __shfl_xor(d3, s);
      }
      float nh[4], ne[4];
#pragma unroll
      for (int j = 0; j < 4; ++j) {
        nh[j] = h[j] * d0 + e[j] * d1 + bc;
        ne[j] = h[j] * d2 + e[j] * d3 + be;
      }
#pragma unroll
      for (int j = 0; j < 4; ++j) { h[j] = nh[j]; e[j] = ne[j]; }
    }
    uint2 v;
    v.x = (unsigned)f2bf(e[0]) | ((unsigned)f2bf(e[1]) << 16);
    v.y = (unsigned)f2bf(e[2]) | ((unsigned)f2bf(e[3]) << 16);
    *(uint2*)(high + (size_t)row * 256 + 128 + c) = v;
  } else if (bid < 2352) {
    // 32x32 transpose tiles: src (K x N) fp32 -> dst (N x K) bf16
    int t = bid - 2048;
    const float* src; unsigned short* dst; int N, K, kt, nt;
    if (t < 32)       { src = Wf; dst = wfT; N = 128; K = 256; kt = t >> 2;       nt = t & 3; }
    else if (t < 48)  { t -= 32;  src = Wu; dst = wuT; N = 128; K = 128; kt = t >> 2; nt = t & 3; }
    else if (t < 176) { t -= 48;  src = W0; dst = w0T; N = 512; K = 256; kt = t >> 4; nt = t & 15; }
    else              { t -= 176; src = W1; dst = w1T; N = 256; K = 512; kt = t >> 3; nt = t & 7; }
    {
      int r = tid >> 3, cg = (tid & 7) * 4;
      float4 v = *(const float4*)(src + (size_t)(kt * 32 + r) * N + nt * 32 + cg);
      tile[r][cg + 0] = f2bf(v.x); tile[r][cg + 1] = f2bf(v.y);
      tile[r][cg + 2] = f2bf(v.z); tile[r][cg + 3] = f2bf(v.w);
    }
    __syncthreads();
    {
      int rp = tid >> 3, cg = (tid & 7) * 4;
      uint2 o;
      o.x = (unsigned)tile[cg + 0][rp] | ((unsigned)tile[cg + 1][rp] << 16);
      o.y = (unsigned)tile[cg + 2][rp] | ((unsigned)tile[cg + 3][rp] << 16);
      *(uint2*)(dst + (size_t)(nt * 32 + rp) * K + kt * 32 + cg) = o;
    }
  } else {
    // W2 256x8 -> 8x256
#pragma unroll
    for (int i = 0; i < 8; ++i) {
      int g = tid * 8 + i, k = g >> 3, n = g & 7;
      w2T[n * 256 + k] = f2bf(W2[g]);
    }
  }
}

// ---------------------------------------------------------------------------
// Pipelined phase helpers.
// B tile per step: 128 n-rows x 64 k, staged reg->LDS (4 uint4/thread).
// ---------------------------------------------------------------------------
template <int LDK>
__device__ __forceinline__ void loadB(uint4 (&r)[4],
                                      const unsigned short* __restrict__ p,
                                      int tid) {
#pragma unroll
  for (int i = 0; i < 4; ++i) {
    int chunk = i * 256 + tid, row = chunk >> 3, seg = chunk & 7;
    r[i] = *(const uint4*)(p + (size_t)row * LDK + seg * 8);
  }
}

__device__ __forceinline__ void dsw(unsigned short* b, const uint4 (&r)[4],
                                    int tid) {
#pragma unroll
  for (int i = 0; i < 4; ++i) {
    int chunk = i * 256 + tid, row = chunk >> 3, seg = chunk & 7;
    *(uint4*)&b[row * 72 + seg * 8] = r[i];
  }
}

template <int PASS_STEPS, int LDK>
__device__ __forceinline__ const unsigned short* srcstep(
    const unsigned short* __restrict__ s, int st) {
  return s + (size_t)(st / PASS_STEPS) * 128 * LDK + (st % PASS_STEPS) * 64;
}

// One K-step of MFMAs: wave covers 32 rows x 32 cols, acc[4] = [mi*2+ni].
template <int LDA>
__device__ __forceinline__ void mstep(const unsigned short* A,
                                      const unsigned short* b, int k0,
                                      floatx4* acc, int m16, int quad,
                                      int wave) {
#pragma unroll
  for (int kk = 0; kk < 64; kk += 32) {
    bf16x8 a0 = *(const bf16x8*)&A[m16 * LDA + k0 + kk + quad * 8];
    bf16x8 a1 = *(const bf16x8*)&A[(16 + m16) * LDA + k0 + kk + quad * 8];
    bf16x8 b0 = *(const bf16x8*)&b[(wave * 32 + m16) * 72 + kk + quad * 8];
    bf16x8 b1 = *(const bf16x8*)&b[(wave * 32 + 16 + m16) * 72 + kk + quad * 8];
    acc[0] = __builtin_amdgcn_mfma_f32_16x16x32_bf16(a0, b0, acc[0], 0, 0, 0);
    acc[1] = __builtin_amdgcn_mfma_f32_16x16x32_bf16(a0, b1, acc[1], 0, 0, 0);
    acc[2] = __builtin_amdgcn_mfma_f32_16x16x32_bf16(a1, b0, acc[2], 0, 0, 0);
    acc[3] = __builtin_amdgcn_mfma_f32_16x16x32_bf16(a1, b1, acc[3], 0, 0, 0);
  }
}

// Full pipelined phase: T K-steps (PASS_STEPS per n-pass), 1 barrier/step.
// Hazard proof: ds_write target buf[(t+1)&1] was last READ by mstep at
// iter t-1, whose ds_reads drained at iter t-1's lgkmcnt(0)+barrier.
template <int T, int LDA, int PASS_STEPS, int LDK>
__device__ __forceinline__ void gemm_phase(
    const unsigned short* A, const unsigned short* __restrict__ src,
    unsigned short* b_sh, floatx4* acc, int tid, int m16, int quad, int wave) {
  uint4 r[2][4];
  // prologue: stage step0, prefetch step1 (T >= 2 always)
  loadB<LDK>(r[0], srcstep<PASS_STEPS, LDK>(src, 0), tid);
  dsw(b_sh, r[0], tid);
  loadB<LDK>(r[1], srcstep<PASS_STEPS, LDK>(src, 1), tid);
  PHASE_BAR();
#pragma unroll
  for (int t = 0; t < T; ++t) {
    unsigned short* bcur = b_sh + (t & 1) * 9216;
    unsigned short* bnxt = b_sh + ((t + 1) & 1) * 9216;
    if (t + 2 < T) loadB<LDK>(r[t & 1], srcstep<PASS_STEPS, LDK>(src, t + 2), tid);
    mstep<LDA>(A, bcur, (t % PASS_STEPS) * 64, acc + (t / PASS_STEPS) * 4, m16,
               quad, wave);
    if (t + 1 < T) dsw(bnxt, r[(t + 1) & 1], tid);
    PHASE_BAR();
  }
}

// ---------------------------------------------------------------------------
// K2 fused_mlp: 512 blocks x 32 rows, full per-row pipeline in one block.
// ---------------------------------------------------------------------------
__global__ __launch_bounds__(256, 2) void fused_mlp_kernel(
    const float* __restrict__ features, const unsigned short* __restrict__ wfT,
    const unsigned short* __restrict__ wuT, const float* __restrict__ bf_,
    const float* __restrict__ bu, const unsigned short* __restrict__ high,
    const unsigned short* __restrict__ w0T, const float* __restrict__ b0,
    const unsigned short* __restrict__ w1T, const float* __restrict__ b1,
    const unsigned short* __restrict__ w2T, const float* __restrict__ b2,
    const int* __restrict__ target, float* __restrict__ out) {
  // regionA layout (shorts): [0,8448) feat_sh/A_sh 32x264;
  // [8448,12800) buf0 32x136; [12800,17152) buf1 32x136.
  // x0_sh (32x520 = 16640) aliases [0,16640) after cf phase.
  __shared__ __align__(16) unsigned short regionA[17152];   // 34.3 KB
  __shared__ __align__(16) unsigned short b_sh[2 * 9216];   // 36.9 KB (2 bufs)
  __shared__ __align__(16) unsigned short w2_sh[2048];      //  4.0 KB
  unsigned short* feat_sh = regionA;
  unsigned short* buf0 = regionA + 8448;
  unsigned short* buf1 = regionA + 12800;
  unsigned short* A_sh = regionA;   // 32x264: [cf2 | high_e] concat
  unsigned short* x0_sh = regionA;  // 32x520
  unsigned short* x1_sh = b_sh;     // 32x264 = 16.5 KB <= b_sh

  const int tid = threadIdx.x;
  const int r0 = blockIdx.x * 32;
  const int lane = tid & 63, wave = tid >> 6;
  const int m16 = lane & 15, quad = lane >> 4;

  // prefetch high_e (gather half from K1) into regs; consumed post-L1.
  const int hrow = tid >> 4, hseg = (tid & 15) * 8;
  uint4 hv0 = *(const uint4*)(high + (size_t)(r0 + hrow) * 256 + 128 + hseg);
  uint4 hv1 = *(const uint4*)(high + (size_t)(r0 + 16 + hrow) * 256 + 128 + hseg);
  *(uint4*)&w2_sh[tid * 8] = *(const uint4*)(w2T + tid * 8);

  // stage features fp32->bf16: 2048 float4, 8/thread, coalesced
#pragma unroll
  for (int i = 0; i < 8; ++i) {
    int idx4 = i * 256 + tid;
    int row = idx4 >> 6, c = (idx4 & 63) * 4;
    float4 v = *(const float4*)(features + (size_t)(r0 + row) * 256 + c);
    uint2 o;
    o.x = (unsigned)f2bf(v.x) | ((unsigned)f2bf(v.y) << 16);
    o.y = (unsigned)f2bf(v.z) | ((unsigned)f2bf(v.w) << 16);
    *(uint2*)&feat_sh[row * 264 + c] = o;
  }

  floatx4 acc[4];
  // ---- L1: cf0 = relu(feat @ Wf + bf), K=256, N=128 ----
#pragma unroll
  for (int j = 0; j < 4; ++j) acc[j] = (floatx4){0.f, 0.f, 0.f, 0.f};
  gemm_phase<4, 264, 4, 256>(feat_sh, wfT, b_sh, acc, tid, m16, quad, wave);
#pragma unroll
  for (int mi = 0; mi < 2; ++mi)
#pragma unroll
    for (int ni = 0; ni < 2; ++ni) {
      int col = wave * 32 + ni * 16 + m16;
      float bv = bf_[col];
#pragma unroll
      for (int r = 0; r < 4; ++r)
        buf0[(mi * 16 + quad * 4 + r) * 136 + col] =
            f2bf(fmaxf(acc[mi * 2 + ni][r] + bv, 0.f));
    }
  // high_e -> A_sh[:,128:256] (feat dead; L1's final barrier has passed)
  *(uint4*)&A_sh[hrow * 264 + 128 + hseg] = hv0;
  *(uint4*)&A_sh[(16 + hrow) * 264 + 128 + hseg] = hv1;

  // ---- L2: cf1 = relu(cf0 @ Wu + bu), K=128, N=128 ----
#pragma unroll
  for (int j = 0; j < 4; ++j) acc[j] = (floatx4){0.f, 0.f, 0.f, 0.f};
  gemm_phase<2, 136, 2, 128>(buf0, wuT, b_sh, acc, tid, m16, quad, wave);
#pragma unroll
  for (int mi = 0; mi < 2; ++mi)
#pragma unroll
    for (int ni = 0; ni < 2; ++ni) {
      int col = wave * 32 + ni * 16 + m16;
      float bv = bu[col];
#pragma unroll
      for (int r = 0; r < 4; ++r)
        buf1[(mi * 16 + quad * 4 + r) * 136 + col] =
            f2bf(fmaxf(acc[mi * 2 + ni][r] + bv, 0.f));
    }

  // ---- L3: cf2 = relu(cf1 @ Wu + bu) -> A_sh[:,0:128] ----
#pragma unroll
  for (int j = 0; j < 4; ++j) acc[j] = (floatx4){0.f, 0.f, 0.f, 0.f};
  gemm_phase<2, 136, 2, 128>(buf1, wuT, b_sh, acc, tid, m16, quad, wave);
#pragma unroll
  for (int mi = 0; mi < 2; ++mi)
#pragma unroll
    for (int ni = 0; ni < 2; ++ni) {
      int col = wave * 32 + ni * 16 + m16;
      float bv = bu[col];
#pragma unroll
      for (int r = 0; r < 4; ++r)
        A_sh[(mi * 16 + quad * 4 + r) * 264 + col] =
            f2bf(fmaxf(acc[mi * 2 + ni][r] + bv, 0.f));
    }

  // ---- x0 = relu(A @ W0 + b0), K=256, N=512 as 4 n-passes ----
  floatx4 acc16[16];
#pragma unroll
  for (int j = 0; j < 16; ++j) acc16[j] = (floatx4){0.f, 0.f, 0.f, 0.f};
  gemm_phase<16, 264, 4, 256>(A_sh, w0T, b_sh, acc16, tid, m16, quad, wave);
  // epilogue -> x0_sh (overwrites regionA; all A reads drained at final bar)
#pragma unroll
  for (int np = 0; np < 4; ++np)
#pragma unroll
    for (int mi = 0; mi < 2; ++mi)
#pragma unroll
      for (int ni = 0; ni < 2; ++ni) {
        int col = np * 128 + wave * 32 + ni * 16 + m16;
        float bv = b0[col];
#pragma unroll
        for (int r = 0; r < 4; ++r)
          x0_sh[(mi * 16 + quad * 4 + r) * 520 + col] =
              f2bf(fmaxf(acc16[np * 4 + mi * 2 + ni][r] + bv, 0.f));
      }

  // ---- x1 = relu(x0 @ W1 + b1), K=512, N=256 as 2 n-passes ----
  floatx4 acc8[8];
#pragma unroll
  for (int j = 0; j < 8; ++j) acc8[j] = (floatx4){0.f, 0.f, 0.f, 0.f};
  gemm_phase<16, 520, 8, 512>(x0_sh, w1T, b_sh, acc8, tid, m16, quad, wave);
  // epilogue -> x1_sh aliased over b_sh (all b_sh reads drained at final bar)
#pragma unroll
  for (int np = 0; np < 2; ++np)
#pragma unroll
    for (int mi = 0; mi < 2; ++mi)
#pragma unroll
      for (int ni = 0; ni < 2; ++ni) {
        int col = np * 128 + wave * 32 + ni * 16 + m16;
        float bv = b1[col];
#pragma unroll
        for (int r = 0; r < 4; ++r)
          x1_sh[(mi * 16 + quad * 4 + r) * 264 + col] =
              f2bf(fmaxf(acc8[np * 4 + mi * 2 + ni][r] + bv, 0.f));
      }
  PHASE_BAR();

  // W2 GEMV + softmax: 8 lanes/row, 32 elems/lane
  {
    int row = tid >> 3, q = tid & 7;
    float p[8];
#pragma unroll
    for (int n = 0; n < 8; ++n) p[n] = 0.f;
#pragma unroll
    for (int jb = 0; jb < 4; ++jb) {
      bf16x8 xv = *(const bf16x8*)&x1_sh[row * 264 + q * 32 + jb * 8];
#pragma unroll
      for (int n = 0; n < 8; ++n) {
        bf16x8 wv = *(const bf16x8*)&w2_sh[n * 256 + q * 32 + jb * 8];
#pragma unroll
        for (int j = 0; j < 8; ++j) p[n] += (float)xv[j] * (float)wv[j];
      }
    }
#pragma unroll
    for (int s = 1; s < 8; s <<= 1)
#pragma unroll
      for (int n = 0; n < 8; ++n) p[n] += __shfl_xor(p[n], s);
    if (q == 0) {
      float mx = -1e30f;
#pragma unroll
      for (int n = 0; n < 8; ++n) {
        p[n] = fmaxf(p[n] + b2[n], 0.f);
        mx = fmaxf(mx, p[n]);
      }
      float sum = 0.f;
#pragma unroll
      for (int n = 0; n < 8; ++n) { p[n] = __expf(p[n] - mx); sum += p[n]; }
      const float inv = 1.f / sum;
      const int gr = r0 + row;
      float4 o0 = {p[0] * inv, p[1] * inv, p[2] * inv, p[3] * inv};
      float4 o1 = {p[4] * inv, p[5] * inv, p[6] * inv, p[7] * inv};
      *(float4*)(out + (size_t)gr * 8) = o0;
      *(float4*)(out + (size_t)gr * 8 + 4) = o1;
      out[16384 * 8 + gr] = (float)target[gr];
    }
  }
}

extern "C" void kernel_launch(void* const* d_in, const int* in_sizes, int n_in,
                              void* d_out, int out_size, void* d_ws, size_t ws_size,
                              hipStream_t stream) {
  const float* features = (const float*)d_in[0];
  const int* ent_idx    = (const int*)d_in[1];
  const int* target     = (const int*)d_in[2];
  const float* Wf  = (const float*)d_in[3];
  const float* bf_ = (const float*)d_in[4];
  const float* Wu  = (const float*)d_in[5];
  const float* bu  = (const float*)d_in[6];
  const float* w_cf = (const float*)d_in[7];
  const float* w_fc = (const float*)d_in[8];
  const float* w_ef = (const float*)d_in[9];
  const float* w_fe = (const float*)d_in[10];
  const float* b_c  = (const float*)d_in[11];
  const float* b_e  = (const float*)d_in[12];
  const float* head_tab = (const float*)d_in[13];
  const float* ent_tab  = (const float*)d_in[14];
  const float* W0 = (const float*)d_in[15];
  const float* b0 = (const float*)d_in[16];
  const float* W1 = (const float*)d_in[17];
  const float* b1 = (const float*)d_in[18];
  const float* W2 = (const float*)d_in[19];
  const float* b2 = (const float*)d_in[20];
  float* out = (float*)d_out;

  unsigned short* ws = (unsigned short*)d_ws;
  size_t off = 0;
  auto alloc = [&](size_t n) { unsigned short* p = ws + off; off += n; return p; };
  unsigned short* high = alloc(16384ull * 256);
  unsigned short* wfT  = alloc(32768);
  unsigned short* wuT  = alloc(16384);
  unsigned short* w0T  = alloc(131072);
  unsigned short* w1T  = alloc(131072);
  unsigned short* w2T  = alloc(2048);
  (void)ws_size; (void)in_sizes; (void)n_in; (void)out_size;

  // K1: gather+cross -> high[:,128:256] + weight transposes
  prep_kernel<<<2353, 256, 0, stream>>>(ent_idx, head_tab, ent_tab,
      w_cf, w_fc, w_ef, w_fe, b_c, b_e, Wf, Wu, W0, W1, W2,
      high, wfT, wuT, w0T, w1T, w2T);
  // K2: full fused per-row pipeline (cf chain + x0 + x1 + W2/softmax)
  fused_mlp_kernel<<<512, 256, 0, stream>>>(features, wfT, wuT, bf_, bu,
      high, w0T, b0, w1T, b1, w2T, b2, target, out);
}

// Round 3
// 184.911 us; speedup vs baseline: 1.0955x; 1.0176x over previous
//
#include <hip/hip_runtime.h>
#include <hip/hip_bf16.h>

// CompanyOperationEvaluation R12:
//  - gather+cross folded INTO fused_mlp (T14 issue-early/consume-late):
//    gather loads issued at kernel start, cross_compress computed after L1,
//    result written straight to A_sh[:,128:256]. `high` workspace removed.
//  - prep shrinks to 305 blocks (weight transposes + W2 only).
//  - gemm_phase: register ring deepened 2 -> 3 (lookahead = 2 K-steps,
//    covers ~200-300cyc L2 latency; LDS double-buffer stays 2-deep).
//  - L3 reuses b_sh contents from L2 (same wuT tile): zero staging.
// Pipeline invariant per iter t: [load step t+3 -> r[t%3]] [mfma buf(t&1)]
// [ds_write buf((t+1)&1) from r[(t+1)%3], loaded at t-2] [lgkmcnt(0);
// s_barrier; sched_barrier(0)]. Counted vmcnt at the ds_write comes from
// register deps: 2 newer load-groups stay in flight (never vmcnt(0)).
// Lesson bank: (R2/R6) gather must not sit on the MFMA critical path -> here
// it is issued ~2000cyc before first use; (R5) keep >=8 MFMAs/wave/step;
// (R8) fusion inherits max LDS; (R10) fusion without load-pipelining is
// latency-bound; (R11) 2-phase raw-barrier pipeline verified good.

typedef __bf16 bf16x8 __attribute__((ext_vector_type(8)));
typedef float floatx4 __attribute__((ext_vector_type(4)));

__device__ __forceinline__ unsigned short f2bf(float x) {
  unsigned int u = __builtin_bit_cast(unsigned int, x);
  u = (u + 0x7FFFu + ((u >> 16) & 1u)) >> 16;
  return (unsigned short)u;
}

#define PHASE_BAR()                                      \
  do {                                                   \
    asm volatile("s_waitcnt lgkmcnt(0)" ::: "memory");   \
    __builtin_amdgcn_s_barrier();                        \
    __builtin_amdgcn_sched_barrier(0);                   \
  } while (0)

// ---------------------------------------------------------------------------
// K1 prep: blocks [0,304) 32x32 transpose tiles; block 304 W2.
// ---------------------------------------------------------------------------
__global__ __launch_bounds__(256) void prep_kernel(
    const float* __restrict__ Wf, const float* __restrict__ Wu,
    const float* __restrict__ W0, const float* __restrict__ W1,
    const float* __restrict__ W2,
    unsigned short* __restrict__ wfT, unsigned short* __restrict__ wuT,
    unsigned short* __restrict__ w0T, unsigned short* __restrict__ w1T,
    unsigned short* __restrict__ w2T) {
  __shared__ unsigned short tile[32][34];
  const int bid = blockIdx.x, tid = threadIdx.x;
  if (bid < 304) {
    // 32x32 transpose tiles: src (K x N) fp32 -> dst (N x K) bf16
    int t = bid;
    const float* src; unsigned short* dst; int N, K, kt, nt;
    if (t < 32)       { src = Wf; dst = wfT; N = 128; K = 256; kt = t >> 2;       nt = t & 3; }
    else if (t < 48)  { t -= 32;  src = Wu; dst = wuT; N = 128; K = 128; kt = t >> 2; nt = t & 3; }
    else if (t < 176) { t -= 48;  src = W0; dst = w0T; N = 512; K = 256; kt = t >> 4; nt = t & 15; }
    else              { t -= 176; src = W1; dst = w1T; N = 256; K = 512; kt = t >> 3; nt = t & 7; }
    {
      int r = tid >> 3, cg = (tid & 7) * 4;
      float4 v = *(const float4*)(src + (size_t)(kt * 32 + r) * N + nt * 32 + cg);
      tile[r][cg + 0] = f2bf(v.x); tile[r][cg + 1] = f2bf(v.y);
      tile[r][cg + 2] = f2bf(v.z); tile[r][cg + 3] = f2bf(v.w);
    }
    __syncthreads();
    {
      int rp = tid >> 3, cg = (tid & 7) * 4;
      uint2 o;
      o.x = (unsigned)tile[cg + 0][rp] | ((unsigned)tile[cg + 1][rp] << 16);
      o.y = (unsigned)tile[cg + 2][rp] | ((unsigned)tile[cg + 3][rp] << 16);
      *(uint2*)(dst + (size_t)(nt * 32 + rp) * K + kt * 32 + cg) = o;
    }
  } else {
    // W2 256x8 -> 8x256
#pragma unroll
    for (int i = 0; i < 8; ++i) {
      int g = tid * 8 + i, k = g >> 3, n = g & 7;
      w2T[n * 256 + k] = f2bf(W2[g]);
    }
  }
}

// ---------------------------------------------------------------------------
// Pipelined phase helpers.
// B tile per step: 128 n-rows x 64 k, staged reg->LDS (4 uint4/thread).
// ---------------------------------------------------------------------------
template <int LDK>
__device__ __forceinline__ void loadB(uint4 (&r)[4],
                                      const unsigned short* __restrict__ p,
                                      int tid) {
#pragma unroll
  for (int i = 0; i < 4; ++i) {
    int chunk = i * 256 + tid, row = chunk >> 3, seg = chunk & 7;
    r[i] = *(const uint4*)(p + (size_t)row * LDK + seg * 8);
  }
}

__device__ __forceinline__ void dsw(unsigned short* b, const uint4 (&r)[4],
                                    int tid) {
#pragma unroll
  for (int i = 0; i < 4; ++i) {
    int chunk = i * 256 + tid, row = chunk >> 3, seg = chunk & 7;
    *(uint4*)&b[row * 72 + seg * 8] = r[i];
  }
}

template <int PASS_STEPS, int LDK>
__device__ __forceinline__ const unsigned short* srcstep(
    const unsigned short* __restrict__ s, int st) {
  return s + (size_t)(st / PASS_STEPS) * 128 * LDK + (st % PASS_STEPS) * 64;
}

// One K-step of MFMAs: wave covers 32 rows x 32 cols, acc[4] = [mi*2+ni].
template <int LDA>
__device__ __forceinline__ void mstep(const unsigned short* A,
                                      const unsigned short* b, int k0,
                                      floatx4* acc, int m16, int quad,
                                      int wave) {
#pragma unroll
  for (int kk = 0; kk < 64; kk += 32) {
    bf16x8 a0 = *(const bf16x8*)&A[m16 * LDA + k0 + kk + quad * 8];
    bf16x8 a1 = *(const bf16x8*)&A[(16 + m16) * LDA + k0 + kk + quad * 8];
    bf16x8 b0 = *(const bf16x8*)&b[(wave * 32 + m16) * 72 + kk + quad * 8];
    bf16x8 b1 = *(const bf16x8*)&b[(wave * 32 + 16 + m16) * 72 + kk + quad * 8];
    acc[0] = __builtin_amdgcn_mfma_f32_16x16x32_bf16(a0, b0, acc[0], 0, 0, 0);
    acc[1] = __builtin_amdgcn_mfma_f32_16x16x32_bf16(a0, b1, acc[1], 0, 0, 0);
    acc[2] = __builtin_amdgcn_mfma_f32_16x16x32_bf16(a1, b0, acc[2], 0, 0, 0);
    acc[3] = __builtin_amdgcn_mfma_f32_16x16x32_bf16(a1, b1, acc[3], 0, 0, 0);
  }
}

// Full pipelined phase: T K-steps (PASS_STEPS per n-pass), 1 barrier/step,
// 3-deep register ring (2 K-steps of load lookahead).
// Hazards: ds_write target buf[(t+1)&1] last READ at iter t-1 (drained at
// its lgkmcnt(0)+barrier); r[t%3] reloaded at iter t was ds_written at
// iter t-1 (program order; compiler enforces WAR).
template <int T, int LDA, int PASS_STEPS, int LDK>
__device__ __forceinline__ void gemm_phase(
    const unsigned short* A, const unsigned short* __restrict__ src,
    unsigned short* b_sh, floatx4* acc, int tid, int m16, int quad, int wave) {
  uint4 r[3][4];
  loadB<LDK>(r[0], srcstep<PASS_STEPS, LDK>(src, 0), tid);
  dsw(b_sh, r[0], tid);
  if (T > 1) loadB<LDK>(r[1], srcstep<PASS_STEPS, LDK>(src, 1), tid);
  if (T > 2) loadB<LDK>(r[2], srcstep<PASS_STEPS, LDK>(src, 2), tid);
  PHASE_BAR();
#pragma unroll
  for (int t = 0; t < T; ++t) {
    if (t + 3 < T)
      loadB<LDK>(r[t % 3], srcstep<PASS_STEPS, LDK>(src, t + 3), tid);
    mstep<LDA>(A, b_sh + (t & 1) * 9216, (t % PASS_STEPS) * 64,
               acc + (t / PASS_STEPS) * 4, m16, quad, wave);
    if (t + 1 < T) dsw(b_sh + ((t + 1) & 1) * 9216, r[(t + 1) % 3], tid);
    PHASE_BAR();
  }
}

// ---------------------------------------------------------------------------
// K2 fused_mlp: 512 blocks x 32 rows, full per-row pipeline incl. gather.
// ---------------------------------------------------------------------------
__global__ __launch_bounds__(256, 2) void fused_mlp_kernel(
    const float* __restrict__ features, const int* __restrict__ ent_idx,
    const float* __restrict__ head_tab, const float* __restrict__ ent_tab,
    const float* __restrict__ w_cf, const float* __restrict__ w_fc,
    const float* __restrict__ w_ef, const float* __restrict__ w_fe,
    const float* __restrict__ b_c, const float* __restrict__ b_e,
    const unsigned short* __restrict__ wfT,
    const unsigned short* __restrict__ wuT, const float* __restrict__ bf_,
    const float* __restrict__ bu,
    const unsigned short* __restrict__ w0T, const float* __restrict__ b0,
    const unsigned short* __restrict__ w1T, const float* __restrict__ b1,
    const unsigned short* __restrict__ w2T, const float* __restrict__ b2,
    const int* __restrict__ target, float* __restrict__ out) {
  // regionA layout (shorts): [0,8448) feat_sh/A_sh 32x264;
  // [8448,12800) buf0 32x136; [12800,17152) buf1 32x136.
  // x0_sh (32x520 = 16640) aliases [0,16640) after cf phase.
  __shared__ __align__(16) unsigned short regionA[17152];   // 34.3 KB
  __shared__ __align__(16) unsigned short b_sh[2 * 9216];   // 36.9 KB (2 bufs)
  __shared__ __align__(16) unsigned short w2_sh[2048];      //  4.0 KB
  __shared__ __align__(16) float cw_sh[512];                //  2.0 KB
  unsigned short* feat_sh = regionA;
  unsigned short* buf0 = regionA + 8448;
  unsigned short* buf1 = regionA + 12800;
  unsigned short* A_sh = regionA;   // 32x264: [cf2 | e] concat
  unsigned short* x0_sh = regionA;  // 32x520
  unsigned short* x1_sh = b_sh;     // 32x264 = 16.5 KB <= b_sh

  const int tid = threadIdx.x;
  const int r0 = blockIdx.x * 32;
  const int lane = tid & 63, wave = tid >> 6;
  const int m16 = lane & 15, quad = lane >> 4;

  // ---- gather issue (T14: earliest point; consumed after L1) ----
  // 8 lanes/row, 16 fp32/lane per table.
  const int grow = tid >> 3, gpart = tid & 7;
  const int gidx = ent_idx[r0 + grow];
  const float* hp = head_tab + (size_t)gidx * 128 + gpart * 16;
  const float* ep = ent_tab + (size_t)gidx * 128 + gpart * 16;
  float4 h4[4], e4[4];
#pragma unroll
  for (int j = 0; j < 4; ++j) {
    h4[j] = *(const float4*)(hp + j * 4);
    e4[j] = *(const float4*)(ep + j * 4);
  }
  // cross weights -> LDS (read at cross time, behind L1's barriers)
  if (tid < 128) {
    int a = tid >> 5, o = (tid & 31) * 4;
    const float* s = (a == 0) ? w_cf : (a == 1) ? w_fc : (a == 2) ? w_ef : w_fe;
    *(float4*)&cw_sh[a * 128 + o] = *(const float4*)(s + o);
  }
  *(uint4*)&w2_sh[tid * 8] = *(const uint4*)(w2T + tid * 8);

  // stage features fp32->bf16: 2048 float4, 8/thread, coalesced
#pragma unroll
  for (int i = 0; i < 8; ++i) {
    int idx4 = i * 256 + tid;
    int row = idx4 >> 6, c = (idx4 & 63) * 4;
    float4 v = *(const float4*)(features + (size_t)(r0 + row) * 256 + c);
    uint2 o;
    o.x = (unsigned)f2bf(v.x) | ((unsigned)f2bf(v.y) << 16);
    o.y = (unsigned)f2bf(v.z) | ((unsigned)f2bf(v.w) << 16);
    *(uint2*)&feat_sh[row * 264 + c] = o;
  }

  floatx4 acc[4];
  // ---- L1: cf0 = relu(feat @ Wf + bf), K=256, N=128 ----
#pragma unroll
  for (int j = 0; j < 4; ++j) acc[j] = (floatx4){0.f, 0.f, 0.f, 0.f};
  gemm_phase<4, 264, 4, 256>(feat_sh, wfT, b_sh, acc, tid, m16, quad, wave);
#pragma unroll
  for (int mi = 0; mi < 2; ++mi)
#pragma unroll
    for (int ni = 0; ni < 2; ++ni) {
      int col = wave * 32 + ni * 16 + m16;
      float bv = bf_[col];
#pragma unroll
      for (int r = 0; r < 4; ++r)
        buf0[(mi * 16 + quad * 4 + r) * 136 + col] =
            f2bf(fmaxf(acc[mi * 2 + ni][r] + bv, 0.f));
    }

  // ---- cross_compress x2 (consume gather) -> A_sh[:,128:256] ----
  // feat cols are dead (all L1 A-reads drained at L1's final barrier);
  // next reader of A_sh[:,128:256] is x0, behind L2/L3 barriers.
  {
    float h[16], e[16];
#pragma unroll
    for (int j = 0; j < 4; ++j) {
      h[4 * j + 0] = h4[j].x; h[4 * j + 1] = h4[j].y;
      h[4 * j + 2] = h4[j].z; h[4 * j + 3] = h4[j].w;
      e[4 * j + 0] = e4[j].x; e[4 * j + 1] = e4[j].y;
      e[4 * j + 2] = e4[j].z; e[4 * j + 3] = e4[j].w;
    }
    const float bc = b_c[0], be = b_e[0];
#pragma unroll
    for (int it = 0; it < 2; ++it) {
      float d0 = 0.f, d1 = 0.f, d2 = 0.f, d3 = 0.f;
#pragma unroll
      for (int j = 0; j < 16; ++j) {
        float wcf = cw_sh[0 * 128 + gpart * 16 + j];
        float wfc = cw_sh[1 * 128 + gpart * 16 + j];
        float wef = cw_sh[2 * 128 + gpart * 16 + j];
        float wfe = cw_sh[3 * 128 + gpart * 16 + j];
        d0 += e[j] * wcf; d1 += h[j] * wfc;
        d2 += e[j] * wef; d3 += h[j] * wfe;
      }
#pragma unroll
      for (int s = 1; s < 8; s <<= 1) {
        d0 += __shfl_xor(d0, s); d1 += __shfl_xor(d1, s);
        d2 += __shfl_xor(d2, s); d3 += __shfl_xor(d3, s);
      }
#pragma unroll
      for (int j = 0; j < 16; ++j) {
        float nh = h[j] * d0 + e[j] * d1 + bc;
        float ne = h[j] * d2 + e[j] * d3 + be;
        h[j] = nh; e[j] = ne;
      }
    }
    uint4 o0, o1;
    unsigned* w = (unsigned*)&o0;
#pragma unroll
    for (int j = 0; j < 4; ++j)
      w[j] = (unsigned)f2bf(e[2 * j]) | ((unsigned)f2bf(e[2 * j + 1]) << 16);
    w = (unsigned*)&o1;
#pragma unroll
    for (int j = 0; j < 4; ++j)
      w[j] = (unsigned)f2bf(e[8 + 2 * j]) |
             ((unsigned)f2bf(e[8 + 2 * j + 1]) << 16);
    *(uint4*)&A_sh[grow * 264 + 128 + gpart * 16] = o0;
    *(uint4*)&A_sh[grow * 264 + 128 + gpart * 16 + 8] = o1;
  }

  // ---- L2: cf1 = relu(cf0 @ Wu + bu), K=128, N=128 ----
#pragma unroll
  for (int j = 0; j < 4; ++j) acc[j] = (floatx4){0.f, 0.f, 0.f, 0.f};
  gemm_phase<2, 136, 2, 128>(buf0, wuT, b_sh, acc, tid, m16, quad, wave);
#pragma unroll
  for (int mi = 0; mi < 2; ++mi)
#pragma unroll
    for (int ni = 0; ni < 2; ++ni) {
      int col = wave * 32 + ni * 16 + m16;
      float bv = bu[col];
#pragma unroll
      for (int r = 0; r < 4; ++r)
        buf1[(mi * 16 + quad * 4 + r) * 136 + col] =
            f2bf(fmaxf(acc[mi * 2 + ni][r] + bv, 0.f));
    }

  // ---- L3: cf2 = relu(cf1 @ Wu + bu) -> A_sh[:,0:128] ----
  // b_sh halves still hold wuT steps 0,1 from L2: zero staging.
#pragma unroll
  for (int j = 0; j < 4; ++j) acc[j] = (floatx4){0.f, 0.f, 0.f, 0.f};
  PHASE_BAR();  // buf1 (L2 epilogue ds_writes) visible to all waves
  mstep<136>(buf1, b_sh, 0, acc, m16, quad, wave);
  mstep<136>(buf1, b_sh + 9216, 64, acc, m16, quad, wave);
  PHASE_BAR();  // drain b_sh ds_reads before x0 prologue overwrites b_sh
#pragma unroll
  for (int mi = 0; mi < 2; ++mi)
#pragma unroll
    for (int ni = 0; ni < 2; ++ni) {
      int col = wave * 32 + ni * 16 + m16;
      float bv = bu[col];
#pragma unroll
      for (int r = 0; r < 4; ++r)
        A_sh[(mi * 16 + quad * 4 + r) * 264 + col] =
            f2bf(fmaxf(acc[mi * 2 + ni][r] + bv, 0.f));
    }

  // ---- x0 = relu(A @ W0 + b0), K=256, N=512 as 4 n-passes ----
  floatx4 acc16[16];
#pragma unroll
  for (int j = 0; j < 16; ++j) acc16[j] = (floatx4){0.f, 0.f, 0.f, 0.f};
  gemm_phase<16, 264, 4, 256>(A_sh, w0T, b_sh, acc16, tid, m16, quad, wave);
  // epilogue -> x0_sh (overwrites regionA; all A reads drained at final bar)
#pragma unroll
  for (int np = 0; np < 4; ++np)
#pragma unroll
    for (int mi = 0; mi < 2; ++mi)
#pragma unroll
      for (int ni = 0; ni < 2; ++ni) {
        int col = np * 128 + wave * 32 + ni * 16 + m16;
        float bv = b0[col];
#pragma unroll
        for (int r = 0; r < 4; ++r)
          x0_sh[(mi * 16 + quad * 4 + r) * 520 + col] =
              f2bf(fmaxf(acc16[np * 4 + mi * 2 + ni][r] + bv, 0.f));
      }

  // ---- x1 = relu(x0 @ W1 + b1), K=512, N=256 as 2 n-passes ----
  floatx4 acc8[8];
#pragma unroll
  for (int j = 0; j < 8; ++j) acc8[j] = (floatx4){0.f, 0.f, 0.f, 0.f};
  gemm_phase<16, 520, 8, 512>(x0_sh, w1T, b_sh, acc8, tid, m16, quad, wave);
  // epilogue -> x1_sh aliased over b_sh (all b_sh reads drained at final bar)
#pragma unroll
  for (int np = 0; np < 2; ++np)
#pragma unroll
    for (int mi = 0; mi < 2; ++mi)
#pragma unroll
      for (int ni = 0; ni < 2; ++ni) {
        int col = np * 128 + wave * 32 + ni * 16 + m16;
        float bv = b1[col];
#pragma unroll
        for (int r = 0; r < 4; ++r)
          x1_sh[(mi * 16 + quad * 4 + r) * 264 + col] =
              f2bf(fmaxf(acc8[np * 4 + mi * 2 + ni][r] + bv, 0.f));
      }
  PHASE_BAR();

  // W2 GEMV + softmax: 8 lanes/row, 32 elems/lane
  {
    int row = tid >> 3, q = tid & 7;
    float p[8];
#pragma unroll
    for (int n = 0; n < 8; ++n) p[n] = 0.f;
#pragma unroll
    for (int jb = 0; jb < 4; ++jb) {
      bf16x8 xv = *(const bf16x8*)&x1_sh[row * 264 + q * 32 + jb * 8];
#pragma unroll
      for (int n = 0; n < 8; ++n) {
        bf16x8 wv = *(const bf16x8*)&w2_sh[n * 256 + q * 32 + jb * 8];
#pragma unroll
        for (int j = 0; j < 8; ++j) p[n] += (float)xv[j] * (float)wv[j];
      }
    }
#pragma unroll
    for (int s = 1; s < 8; s <<= 1)
#pragma unroll
      for (int n = 0; n < 8; ++n) p[n] += __shfl_xor(p[n], s);
    if (q == 0) {
      float mx = -1e30f;
#pragma unroll
      for (int n = 0; n < 8; ++n) {
        p[n] = fmaxf(p[n] + b2[n], 0.f);
        mx = fmaxf(mx, p[n]);
      }
      float sum = 0.f;
#pragma unroll
      for (int n = 0; n < 8; ++n) { p[n] = __expf(p[n] - mx); sum += p[n]; }
      const float inv = 1.f / sum;
      const int gr = r0 + row;
      float4 o0 = {p[0] * inv, p[1] * inv, p[2] * inv, p[3] * inv};
      float4 o1 = {p[4] * inv, p[5] * inv, p[6] * inv, p[7] * inv};
      *(float4*)(out + (size_t)gr * 8) = o0;
      *(float4*)(out + (size_t)gr * 8 + 4) = o1;
      out[16384 * 8 + gr] = (float)target[gr];
    }
  }
}

extern "C" void kernel_launch(void* const* d_in, const int* in_sizes, int n_in,
                              void* d_out, int out_size, void* d_ws, size_t ws_size,
                              hipStream_t stream) {
  const float* features = (const float*)d_in[0];
  const int* ent_idx    = (const int*)d_in[1];
  const int* target     = (const int*)d_in[2];
  const float* Wf  = (const float*)d_in[3];
  const float* bf_ = (const float*)d_in[4];
  const float* Wu  = (const float*)d_in[5];
  const float* bu  = (const float*)d_in[6];
  const float* w_cf = (const float*)d_in[7];
  const float* w_fc = (const float*)d_in[8];
  const float* w_ef = (const float*)d_in[9];
  const float* w_fe = (const float*)d_in[10];
  const float* b_c  = (const float*)d_in[11];
  const float* b_e  = (const float*)d_in[12];
  const float* head_tab = (const float*)d_in[13];
  const float* ent_tab  = (const float*)d_in[14];
  const float* W0 = (const float*)d_in[15];
  const float* b0 = (const float*)d_in[16];
  const float* W1 = (const float*)d_in[17];
  const float* b1 = (const float*)d_in[18];
  const float* W2 = (const float*)d_in[19];
  const float* b2 = (const float*)d_in[20];
  float* out = (float*)d_out;

  unsigned short* ws = (unsigned short*)d_ws;
  size_t off = 0;
  auto alloc = [&](size_t n) { unsigned short* p = ws + off; off += n; return p; };
  unsigned short* wfT  = alloc(32768);
  unsigned short* wuT  = alloc(16384);
  unsigned short* w0T  = alloc(131072);
  unsigned short* w1T  = alloc(131072);
  unsigned short* w2T  = alloc(2048);
  (void)ws_size; (void)in_sizes; (void)n_in; (void)out_size;

  // K1: weight transposes only
  prep_kernel<<<305, 256, 0, stream>>>(Wf, Wu, W0, W1, W2,
                                       wfT, wuT, w0T, w1T, w2T);
  // K2: full fused per-row pipeline (gather+cross + cf chain + x0 + x1 +
  // W2/softmax)
  fused_mlp_kernel<<<512, 256, 0, stream>>>(features, ent_idx, head_tab,
      ent_tab, w_cf, w_fc, w_ef, w_fe, b_c, b_e, wfT, wuT, bf_, bu,
      w0T, b0, w1T, b1, w2T, b2, target, out);
}